// Round 6
// baseline (189.783 us; speedup 1.0000x reference)
//
#include <hip/hip_runtime.h>

#define BB 16
#define CC 2
#define TT 1000
#define FF 257
#define NBC (BB * CC)                               // 32
#define NCHAIN (NBC * FF)                           // 8224
#define RES_ELEMS ((size_t)BB * CC * TT * FF * 2)   // 16,448,000

#define LCH 40          // timesteps per chunk
#define KCH 25          // chunks per chain (25*40 = 1000 exact, uniform)
#define FBLK 4          // full 64-wide f blocks (f in [0,256))
#define FULLW (NBC * KCH * FBLK)            // 3200 full waves
#define STRAG (NBC * KCH)                   // 800 straggler (bc,k) pairs, f == 256
#define NTHR 512
#define WPB (NTHR / 64)                     // 8 waves per block
#define NWAVE (FULLW + (STRAG + 63) / 64)   // 3213
#define NBLK ((NWAVE + WPB - 1) / WPB)      // 402 blocks

// Wave->work map shared by both kernels: wave owns 64 CONSECUTIVE f of one
// (bc, chunk k) -> every global load/store instruction is one contiguous,
// fully-used 512 B segment (rounds 0-4: 4 scattered 128 B segments, delivered
// BW pinned ~3 TB/s). No cooperative launch (round-5 failure): the cross-chunk
// dependency flows through d_ws between two stream-ordered kernels.
__device__ __forceinline__ bool wave_map(int W, int lane,
                                         int& bc, int& k, int& f) {
    if (W < FULLW) {
        bc = W / (KCH * FBLK);
        const int r = W % (KCH * FBLK);
        k = r / FBLK;
        f = (r % FBLK) * 64 + lane;
        return true;
    }
    const int idx = (W - FULLW) * 64 + lane;    // packed f==256 stragglers
    if (idx < STRAG) { bc = idx / KCH; k = idx % KCH; f = FF - 1; return true; }
    return false;
}

// K1: per-(chain,chunk) scan-from-zero end value -> e_ws. Pure stream, no LDS,
// no register buffer.
__global__ __launch_bounds__(NTHR, 4) void fnorm_sums(
    const float* __restrict__ input,
    const float* __restrict__ alpha,
    float* __restrict__ e_ws)
{
    const int W    = blockIdx.x * WPB + (threadIdx.x >> 6);
    const int lane = threadIdx.x & 63;
    int bc, k, f;
    if (!wave_map(W, lane, bc, k, f)) return;

    const int cf = (bc & 1) * FF + f;
    const float av = 1.0f / (1.0f + __expf(-alpha[cf]));
    const float om = 1.0f - av;

    const float2* __restrict__ in2 =
        (const float2*)input + (size_t)bc * (TT * FF) + (size_t)(k * LCH) * FF + f;

    float s = 0.0f;
    #pragma unroll
    for (int t = 0; t < LCH; ++t) {
        float2 v = in2[(size_t)t * FF];
        s = fmaf(fmaf(v.x, v.x, v.y * v.y), av, s * om);
    }
    e_ws[k * NCHAIN + bc * FF + f] = s;
}

// K2: rebuild chunk init state from s1 + e_ws (p = om^40 uniform), then rescan.
// Input re-read hits the 256 MB L3 (K1 just streamed it); stores are the only
// HBM writes and are fully contiguous.
__global__ __launch_bounds__(NTHR, 4) void fnorm_rescan(
    const float* __restrict__ input,
    const float* __restrict__ weights,
    const float* __restrict__ bias,
    const float* __restrict__ alpha,
    const float* __restrict__ s1,
    float* __restrict__ out,
    const float* __restrict__ e_ws)
{
    const int W    = blockIdx.x * WPB + (threadIdx.x >> 6);
    const int lane = threadIdx.x & 63;
    int bc, k, f;
    if (!wave_map(W, lane, bc, k, f)) return;

    const int cf = (bc & 1) * FF + f;
    const float av = 1.0f / (1.0f + __expf(-alpha[cf]));
    const float om = 1.0f - av;
    const float w  = weights[cf];
    const float bi = bias[cf];

    // p = om^40 by squarings (uniform chunk length, exact 40)
    const float om2 = om * om, om4 = om2 * om2, om8 = om4 * om4;
    const float om16 = om8 * om8, om32 = om16 * om16;
    const float p = om32 * om8;

    const int chain = bc * FF + f;
    float S = s1[chain];
    for (int kk = 0; kk < k; ++kk)                   // k uniform per full wave
        S = fmaf(S, p, e_ws[kk * NCHAIN + chain]);   // 256 B coalesced, L2-hot

    const size_t base = (size_t)bc * (TT * FF) + (size_t)(k * LCH) * FF + f;
    const float2* __restrict__ in2  = (const float2*)input + base;
    float2* __restrict__ out2       = (float2*)out + base;

    float s = S;
    #pragma unroll
    for (int t = 0; t < LCH; ++t) {
        float2 v = in2[(size_t)t * FF];
        float d2 = fmaf(v.x, v.x, v.y * v.y);
        s = fmaf(d2, av, s * om);
        float inv = __frsqrt_rn(s + 1e-16f) * w;
        float2 y;
        y.x = fmaf(v.x, inv, bi);
        y.y = fmaf(v.y, inv, bi);
        out2[(size_t)t * FF] = y;
    }
    if (k == KCH - 1)
        out[RES_ELEMS + (size_t)chain] = s;          // s_last
}

extern "C" void kernel_launch(void* const* d_in, const int* in_sizes, int n_in,
                              void* d_out, int out_size, void* d_ws, size_t ws_size,
                              hipStream_t stream) {
    const float* input   = (const float*)d_in[0];
    const float* weights = (const float*)d_in[1];
    const float* bias    = (const float*)d_in[2];
    const float* alpha   = (const float*)d_in[3];
    const float* s1      = (const float*)d_in[4];
    float* out  = (float*)d_out;
    float* e_ws = (float*)d_ws;   // KCH*NCHAIN*4 = 822 KB

    dim3 grid(NBLK), block(NTHR);
    hipLaunchKernelGGL(fnorm_sums,   grid, block, 0, stream, input, alpha, e_ws);
    hipLaunchKernelGGL(fnorm_rescan, grid, block, 0, stream,
                       input, weights, bias, alpha, s1, out, e_ws);
}

// Round 7
// 158.484 us; speedup vs baseline: 1.1975x; 1.1975x over previous
//
#include <hip/hip_runtime.h>

#define BB 16
#define CC 2
#define TT 1000
#define FF 257
#define NBC (BB * CC)                               // 32
#define NCHAIN (NBC * FF)                           // 8224
#define RES_ELEMS ((size_t)BB * CC * TT * FF * 2)   // 16,448,000

// ---------------- main kernel: f in [0,256) as 128 pairs per bc ----------------
#define FPB 8           // f-pairs per block (threadIdx.x)
#define KCH 64          // chunks per chain (threadIdx.y)
#define LCH 16          // timesteps per chunk (64*16 = 1024 >= 1000)
#define NPAIR (NBC * 128)                // 4096 pair-chains
#define NBLK (NPAIR / FPB)               // 512 blocks == exactly 2/CU capacity

// Theory: all float2-based rounds (R0/R1/R3/R4) pinned at ~3.0 TB/s moving
// 512 B per VMEM wave-instruction; m13's float4 copy (1 KB/instr) hits 6.3.
// => cap is VMEM instruction issue rate; double bytes/instruction via paired
// chains + dwordx4. Odd-t rows are only 8B-aligned (row stride 2056 B) —
// deliberate bet that gfx950 global dwordx4 handles dword-aligned addrs.
__global__ __launch_bounds__(512, 4) void fnorm_main(
    const float* __restrict__ input,
    const float* __restrict__ weights,
    const float* __restrict__ bias,
    const float* __restrict__ alpha,
    const float* __restrict__ s1,
    float* __restrict__ out)
{
    const int tx = threadIdx.x;                  // pair-in-block 0..7
    const int ky = threadIdx.y;                  // chunk 0..63
    const int P  = blockIdx.x * FPB + tx;        // 0..4095
    const int bc = P >> 7;                       // 128 pairs per bc, no straddle
    const int f  = (P & 127) * 2;                // even f
    const int cf = (bc & 1) * FF + f;

    const float av_a = 1.0f / (1.0f + __expf(-alpha[cf]));
    const float av_b = 1.0f / (1.0f + __expf(-alpha[cf + 1]));
    const float om_a = 1.0f - av_a, om_b = 1.0f - av_b;
    const float w_a = weights[cf],  w_b = weights[cf + 1];
    const float bi_a = bias[cf],    bi_b = bias[cf + 1];

    const float* __restrict__ ibase = input + (size_t)bc * (TT * FF * 2) + 2 * f;
    float* __restrict__ obase       = out   + (size_t)bc * (TT * FF * 2) + 2 * f;

    const int t0 = ky * LCH;
    const int n  = (TT - t0) < LCH ? ((TT - t0) < 0 ? 0 : (TT - t0)) : LCH; // 16/8/0

    // Phase A: dwordx4 loads into register buffer (2 chains x LCH steps).
    float4 x[LCH];
    #pragma unroll
    for (int t = 0; t < LCH; ++t)
        if (t < n) x[t] = *(const float4*)(ibase + (size_t)(t0 + t) * (FF * 2));

    float sa = 0.f, sb = 0.f, pa = 1.f, pb = 1.f;
    #pragma unroll
    for (int t = 0; t < LCH; ++t) {
        if (t < n) {
            float4 v = x[t];
            sa = fmaf(fmaf(v.x, v.x, v.y * v.y), av_a, sa * om_a); pa *= om_a;
            sb = fmaf(fmaf(v.z, v.z, v.w * v.w), av_b, sb * om_b); pb *= om_b;
        }
    }

    // Fix-up: 16 chains x 64 chunks of affine maps S -> p*S + e; two width-64
    // shuffle-scan passes (8 waves x 2).
    __shared__ float p_s[KCH][2 * FPB + 1];   // stride 17 (odd): 2-way max on scan read
    __shared__ float e_s[KCH][2 * FPB + 1];
    __shared__ float i_s[KCH][2 * FPB + 1];
    p_s[ky][2 * tx] = pa;  p_s[ky][2 * tx + 1] = pb;
    e_s[ky][2 * tx] = sa;  e_s[ky][2 * tx + 1] = sb;
    __syncthreads();
    {
        const int tid  = tx + ky * FPB;
        const int lane = tid & 63;               // chunk index
        const int wv   = tid >> 6;               // 0..7
        #pragma unroll
        for (int h = 0; h < 2; ++h) {
            const int ch = wv + 8 * h;           // chain-in-block 0..15
            const int Pc = blockIdx.x * FPB + (ch >> 1);
            const int chain = (Pc >> 7) * FF + (Pc & 127) * 2 + (ch & 1);
            float pp = p_s[lane][ch];
            float ee = e_s[lane][ch];
            #pragma unroll
            for (int d = 1; d < 64; d <<= 1) {
                float pu = __shfl_up(pp, d, 64);
                float eu = __shfl_up(ee, d, 64);
                if (lane >= d) { ee = fmaf(pp, eu, ee); pp *= pu; }
            }
            const float S0 = s1[chain];
            float Sin = fmaf(pp, S0, ee);
            float Sex = __shfl_up(Sin, 1, 64);
            if (lane == 0) Sex = S0;
            i_s[lane][ch] = Sex;
            if (lane == 63) out[RES_ELEMS + (size_t)chain] = Sin;   // s_last
        }
    }
    __syncthreads();

    // Phase B: rescan from registers, dwordx4 stores.
    float s_a = i_s[ky][2 * tx], s_b = i_s[ky][2 * tx + 1];
    #pragma unroll
    for (int t = 0; t < LCH; ++t) {
        if (t < n) {
            float4 v = x[t];
            s_a = fmaf(fmaf(v.x, v.x, v.y * v.y), av_a, s_a * om_a);
            s_b = fmaf(fmaf(v.z, v.z, v.w * v.w), av_b, s_b * om_b);
            float ia = __frsqrt_rn(s_a + 1e-16f) * w_a;
            float ib = __frsqrt_rn(s_b + 1e-16f) * w_b;
            float4 y;
            y.x = fmaf(v.x, ia, bi_a); y.y = fmaf(v.y, ia, bi_a);
            y.z = fmaf(v.z, ib, bi_b); y.w = fmaf(v.w, ib, bi_b);
            *(float4*)(obase + (size_t)(t0 + t) * (FF * 2)) = y;
        }
    }
}

// ---------------- straggler kernel: the f == 256 column (32 chains) ----------------
// One wave per chain; lane = 16-step chunk; width-64 shuffle affine scan.
__global__ __launch_bounds__(512) void fnorm_straggler(
    const float* __restrict__ input,
    const float* __restrict__ weights,
    const float* __restrict__ bias,
    const float* __restrict__ alpha,
    const float* __restrict__ s1,
    float* __restrict__ out)
{
    const int wv   = threadIdx.x >> 6;
    const int lane = threadIdx.x & 63;
    const int bc   = blockIdx.x * 8 + wv;        // 0..31
    const int f    = FF - 1;
    const int cf   = (bc & 1) * FF + f;
    const int chain = bc * FF + f;

    const float av = 1.0f / (1.0f + __expf(-alpha[cf]));
    const float om = 1.0f - av;
    const float w  = weights[cf];
    const float bi = bias[cf];

    const float2* __restrict__ in2 = (const float2*)input + (size_t)bc * (TT * FF) + f;
    float2* __restrict__ out2      = (float2*)out        + (size_t)bc * (TT * FF) + f;

    const int t0 = lane * 16;
    const int n  = (TT - t0) < 16 ? ((TT - t0) < 0 ? 0 : (TT - t0)) : 16;

    float2 x[16];
    #pragma unroll
    for (int t = 0; t < 16; ++t)
        if (t < n) x[t] = in2[(size_t)(t0 + t) * FF];

    float ee = 0.f, pp = 1.f;
    #pragma unroll
    for (int t = 0; t < 16; ++t) {
        if (t < n) {
            float2 v = x[t];
            ee = fmaf(fmaf(v.x, v.x, v.y * v.y), av, ee * om);
            pp *= om;
        }
    }
    #pragma unroll
    for (int d = 1; d < 64; d <<= 1) {
        float pu = __shfl_up(pp, d, 64);
        float eu = __shfl_up(ee, d, 64);
        if (lane >= d) { ee = fmaf(pp, eu, ee); pp *= pu; }
    }
    const float S0 = s1[chain];
    float Sin = fmaf(pp, S0, ee);
    float Sex = __shfl_up(Sin, 1, 64);
    if (lane == 0) Sex = S0;
    if (lane == 63) out[RES_ELEMS + (size_t)chain] = Sin;   // s_last

    float s = Sex;
    #pragma unroll
    for (int t = 0; t < 16; ++t) {
        if (t < n) {
            float2 v = x[t];
            s = fmaf(fmaf(v.x, v.x, v.y * v.y), av, s * om);
            float inv = __frsqrt_rn(s + 1e-16f) * w;
            float2 y;
            y.x = fmaf(v.x, inv, bi);
            y.y = fmaf(v.y, inv, bi);
            out2[(size_t)(t0 + t) * FF] = y;
        }
    }
}

extern "C" void kernel_launch(void* const* d_in, const int* in_sizes, int n_in,
                              void* d_out, int out_size, void* d_ws, size_t ws_size,
                              hipStream_t stream) {
    const float* input   = (const float*)d_in[0];
    const float* weights = (const float*)d_in[1];
    const float* bias    = (const float*)d_in[2];
    const float* alpha   = (const float*)d_in[3];
    const float* s1      = (const float*)d_in[4];
    float* out = (float*)d_out;

    hipLaunchKernelGGL(fnorm_straggler, dim3(4), dim3(512), 0, stream,
                       input, weights, bias, alpha, s1, out);
    hipLaunchKernelGGL(fnorm_main, dim3(NBLK), dim3(FPB, KCH), 0, stream,
                       input, weights, bias, alpha, s1, out);
}

// Round 8
// 147.933 us; speedup vs baseline: 1.2829x; 1.0713x over previous
//
#include <hip/hip_runtime.h>

#define BB 16
#define CC 2
#define TT 1000
#define FF 257
#define NBC (BB * CC)                               // 32
#define NCHAIN (NBC * FF)                           // 8224
#define RES_ELEMS ((size_t)BB * CC * TT * FF * 2)   // 16,448,000

#define TC 20                    // timesteps per tile
#define KC (TT / TC)             // 50 chunks per bc (50*20 = 1000 exact)
#define ROWF (FF * 2)            // 514 floats per t-row (contiguous)
#define TILEF (TC * ROWF)        // 10280 floats per tile = 41120 B (16B-aligned)
#define TILE4 (TILEF / 4)        // 2570 float4 per tile
#define NTHR 512
#define NBLK (NBC * KC)          // 1600 blocks

// DRAM-row theory: all prior kernels (3.0 TB/s) walk t-columns at 2056 B row
// stride -> each HBM row is visited piecewise by uncorrelated waves (row-buffer
// thrash, ~2x activation cost). A (bc, t-chunk) tile with FULL f-range is one
// CONTIGUOUS region -> each block streams sequentially like the 6.3 TB/s copy
// bench. Scan runs along t inside LDS; chunk summaries cross blocks via e_ws
// between two stream-ordered kernels (cooperative launch failed in R5).

// K1: per-(chain, chunk) scan-from-zero end values -> e_ws.
__global__ __launch_bounds__(NTHR, 4) void fnorm_sums(
    const float* __restrict__ input,
    const float* __restrict__ alpha,
    float* __restrict__ e_ws)
{
    __shared__ float lds[TILEF];
    const int bc = blockIdx.x / KC;
    const int k  = blockIdx.x % KC;

    // Sequential tile load: one contiguous 41120 B region per block.
    const float4* __restrict__ src =
        (const float4*)(input + (size_t)bc * (TT * ROWF) + (size_t)k * TILEF);
    for (int i = threadIdx.x; i < TILE4; i += NTHR)
        ((float4*)lds)[i] = src[i];
    __syncthreads();

    const int f = threadIdx.x;
    if (f < FF) {
        const int cf = (bc & 1) * FF + f;
        const float av = 1.0f / (1.0f + __expf(-alpha[cf]));
        const float om = 1.0f - av;
        float s = 0.0f;
        #pragma unroll
        for (int t = 0; t < TC; ++t) {
            float2 v = ((const float2*)lds)[t * FF + f];   // stride-1 over lanes
            s = fmaf(fmaf(v.x, v.x, v.y * v.y), av, s * om);
        }
        e_ws[k * NCHAIN + bc * FF + f] = s;
    }
}

// K2: rebuild init state from s1 + e_ws prefix (p = om^20 uniform), rescan the
// tile in LDS, write transformed tile back sequentially.
__global__ __launch_bounds__(NTHR, 4) void fnorm_apply(
    const float* __restrict__ input,
    const float* __restrict__ weights,
    const float* __restrict__ bias,
    const float* __restrict__ alpha,
    const float* __restrict__ s1,
    float* __restrict__ out,
    const float* __restrict__ e_ws)
{
    __shared__ float lds[TILEF];
    const int bc = blockIdx.x / KC;
    const int k  = blockIdx.x % KC;

    const size_t base = (size_t)bc * (TT * ROWF) + (size_t)k * TILEF;
    const float4* __restrict__ src = (const float4*)(input + base);
    for (int i = threadIdx.x; i < TILE4; i += NTHR)
        ((float4*)lds)[i] = src[i];
    // (no barrier yet: prefix below only touches global memory)

    const int f = threadIdx.x;
    float s = 0.0f, av = 0.0f, om = 0.0f, w = 0.0f, bi = 0.0f;
    if (f < FF) {
        const int cf = (bc & 1) * FF + f;
        av = 1.0f / (1.0f + __expf(-alpha[cf]));
        om = 1.0f - av;
        w  = weights[cf];
        bi = bias[cf];
        const float om2 = om * om, om4 = om2 * om2;
        const float om8 = om4 * om4, om16 = om8 * om8;
        const float p = om16 * om4;                    // om^20 exact-chunk decay

        const int chain = bc * FF + f;
        s = s1[chain];
        // Unrolled + predicated: 49 INDEPENDENT L2-hot loads the compiler can
        // hoist ahead of the serial fma chain (runtime-indexed array would go
        // to scratch; a rolled loop would serialize load latency per step).
        #pragma unroll
        for (int kk = 0; kk < KC - 1; ++kk) {
            if (kk < k) s = fmaf(s, p, e_ws[kk * NCHAIN + chain]);
        }
    }
    __syncthreads();                                   // tile resident in LDS

    if (f < FF) {
        #pragma unroll
        for (int t = 0; t < TC; ++t) {
            float2 v = ((const float2*)lds)[t * FF + f];
            s = fmaf(fmaf(v.x, v.x, v.y * v.y), av, s * om);
            const float inv = __frsqrt_rn(s + 1e-16f) * w;
            float2 y;
            y.x = fmaf(v.x, inv, bi);
            y.y = fmaf(v.y, inv, bi);
            ((float2*)lds)[t * FF + f] = y;            // in-place transform
        }
        if (k == KC - 1)
            out[RES_ELEMS + (size_t)(bc * FF + f)] = s;   // s_last
    }
    __syncthreads();

    // Sequential tile store.
    float4* __restrict__ dst = (float4*)(out + base);
    for (int i = threadIdx.x; i < TILE4; i += NTHR)
        dst[i] = ((const float4*)lds)[i];
}

extern "C" void kernel_launch(void* const* d_in, const int* in_sizes, int n_in,
                              void* d_out, int out_size, void* d_ws, size_t ws_size,
                              hipStream_t stream) {
    const float* input   = (const float*)d_in[0];
    const float* weights = (const float*)d_in[1];
    const float* bias    = (const float*)d_in[2];
    const float* alpha   = (const float*)d_in[3];
    const float* s1      = (const float*)d_in[4];
    float* out  = (float*)d_out;
    float* e_ws = (float*)d_ws;   // KC*NCHAIN*4 = 1.64 MB

    dim3 grid(NBLK), block(NTHR);
    hipLaunchKernelGGL(fnorm_sums,  grid, block, 0, stream, input, alpha, e_ws);
    hipLaunchKernelGGL(fnorm_apply, grid, block, 0, stream,
                       input, weights, bias, alpha, s1, out, e_ws);
}

// Round 9
// 137.465 us; speedup vs baseline: 1.3806x; 1.0762x over previous
//
#include <hip/hip_runtime.h>

#define BB 16
#define CC 2
#define TT 1000
#define FF 257
#define NBC (BB * CC)                               // 32
#define NCHAIN (NBC * FF)                           // 8224
#define RES_ELEMS ((size_t)BB * CC * TT * FF * 2)   // 16,448,000

#define TC 10                    // timesteps per tile
#define KC (TT / TC)             // 100 chunks per bc (100*10 = 1000 exact)
#define ROWF (FF * 2)            // 514 floats per t-row (contiguous)
#define TILEF (TC * ROWF)        // 5140 floats = 20560 B (16B-aligned per tile)
#define TILE4 (TILEF / 4)        // 1285 float4 per tile
#define NTHR 320                 // 5 waves; LDS 20.6 KB -> 6 blocks/CU resident
#define NBLK (NBC * KC)          // 3200 blocks (12.5 per CU, 6-deep overlap)
#define PBATCH 20                // prefix-kernel load batch (static reg indexing)

// R8 evidence: sequential-tile K1 ran ~4.2 TB/s (theory confirmed for reads);
// K2 was 2.6x over roofline. Diagnosis: per-block serial e_ws prefix chain
// (predicated loads -> unhoistable -> ~200cyc/step latency) + 2 barriers +
// only 3 blocks/CU of phase overlap. This version: prefix moved to a tiny
// thread-per-chain kernel (batched loads, in-place e->init overwrite of ws),
// and smaller tiles (TC=10, 320 thr) double block residency to 6/CU.

// K1: per-(chain, chunk) scan-from-zero end values -> ws.
__global__ __launch_bounds__(NTHR, 4) void fnorm_sums(
    const float* __restrict__ input,
    const float* __restrict__ alpha,
    float* __restrict__ ws)
{
    __shared__ float lds[TILEF];
    const int bc = blockIdx.x / KC;
    const int k  = blockIdx.x % KC;

    const float4* __restrict__ src =
        (const float4*)(input + (size_t)bc * (TT * ROWF) + (size_t)k * TILEF);
    for (int i = threadIdx.x; i < TILE4; i += NTHR)
        ((float4*)lds)[i] = src[i];
    __syncthreads();

    const int f = threadIdx.x;
    if (f < FF) {
        const int cf = (bc & 1) * FF + f;
        const float av = 1.0f / (1.0f + __expf(-alpha[cf]));
        const float om = 1.0f - av;
        float s = 0.0f;
        #pragma unroll
        for (int t = 0; t < TC; ++t) {
            float2 v = ((const float2*)lds)[t * FF + f];
            s = fmaf(fmaf(v.x, v.x, v.y * v.y), av, s * om);
        }
        ws[k * NCHAIN + bc * FF + f] = s;
    }
}

// K_mid: thread-per-chain exclusive scan over the 100 chunk summaries,
// IN PLACE (ws: end-values -> init-states). Batched loads (20 regs, static
// indices) decouple L2 latency from the serial fma chain. Writes s_last.
__global__ __launch_bounds__(256) void fnorm_prefix(
    const float* __restrict__ alpha,
    const float* __restrict__ s1,
    float* __restrict__ out,
    float* ws)
{
    const int ch = blockIdx.x * 256 + threadIdx.x;
    if (ch >= NCHAIN) return;
    const int f  = ch % FF;
    const int bc = ch / FF;
    const int cf = (bc & 1) * FF + f;

    const float av = 1.0f / (1.0f + __expf(-alpha[cf]));
    const float om = 1.0f - av;
    const float om2 = om * om, om4 = om2 * om2, om8 = om4 * om4;
    const float p = om8 * om2;                      // om^10: per-chunk decay

    float S = s1[ch];
    float e[PBATCH];
    for (int kb = 0; kb < KC; kb += PBATCH) {
        #pragma unroll
        for (int j = 0; j < PBATCH; ++j)            // independent, hoistable
            e[j] = ws[(kb + j) * NCHAIN + ch];
        #pragma unroll
        for (int j = 0; j < PBATCH; ++j) {
            ws[(kb + j) * NCHAIN + ch] = S;         // exclusive: init state
            S = fmaf(S, p, e[j]);
        }
    }
    out[RES_ELEMS + (size_t)ch] = S;                // s_last
}

// K2: load init state (one coalesced read), rescan tile in LDS, store tile
// sequentially. No serial chains, no prefix work.
__global__ __launch_bounds__(NTHR, 4) void fnorm_apply(
    const float* __restrict__ input,
    const float* __restrict__ weights,
    const float* __restrict__ bias,
    const float* __restrict__ alpha,
    float* __restrict__ out,
    const float* __restrict__ ws)
{
    __shared__ float lds[TILEF];
    const int bc = blockIdx.x / KC;
    const int k  = blockIdx.x % KC;

    const size_t base = (size_t)bc * (TT * ROWF) + (size_t)k * TILEF;
    const float4* __restrict__ src = (const float4*)(input + base);
    for (int i = threadIdx.x; i < TILE4; i += NTHR)
        ((float4*)lds)[i] = src[i];

    const int f = threadIdx.x;
    float s = 0.f, av = 0.f, om = 0.f, w = 0.f, bi = 0.f;
    if (f < FF) {
        const int cf = (bc & 1) * FF + f;
        av = 1.0f / (1.0f + __expf(-alpha[cf]));
        om = 1.0f - av;
        w  = weights[cf];
        bi = bias[cf];
        s  = ws[k * NCHAIN + bc * FF + f];          // init state, coalesced
    }
    __syncthreads();

    if (f < FF) {
        #pragma unroll
        for (int t = 0; t < TC; ++t) {
            float2 v = ((const float2*)lds)[t * FF + f];
            s = fmaf(fmaf(v.x, v.x, v.y * v.y), av, s * om);
            const float inv = __frsqrt_rn(s + 1e-16f) * w;
            float2 y;
            y.x = fmaf(v.x, inv, bi);
            y.y = fmaf(v.y, inv, bi);
            ((float2*)lds)[t * FF + f] = y;
        }
    }
    __syncthreads();

    float4* __restrict__ dst = (float4*)(out + base);
    for (int i = threadIdx.x; i < TILE4; i += NTHR)
        dst[i] = ((const float4*)lds)[i];
}

extern "C" void kernel_launch(void* const* d_in, const int* in_sizes, int n_in,
                              void* d_out, int out_size, void* d_ws, size_t ws_size,
                              hipStream_t stream) {
    const float* input   = (const float*)d_in[0];
    const float* weights = (const float*)d_in[1];
    const float* bias    = (const float*)d_in[2];
    const float* alpha   = (const float*)d_in[3];
    const float* s1      = (const float*)d_in[4];
    float* out = (float*)d_out;
    float* ws  = (float*)d_ws;   // KC*NCHAIN*4 = 3.29 MB

    hipLaunchKernelGGL(fnorm_sums, dim3(NBLK), dim3(NTHR), 0, stream,
                       input, alpha, ws);
    hipLaunchKernelGGL(fnorm_prefix, dim3((NCHAIN + 255) / 256), dim3(256), 0,
                       stream, alpha, s1, out, ws);
    hipLaunchKernelGGL(fnorm_apply, dim3(NBLK), dim3(NTHR), 0, stream,
                       input, weights, bias, alpha, out, ws);
}